// Round 3
// baseline (699.638 us; speedup 1.0000x reference)
//
#include <hip/hip_runtime.h>
#include <math.h>

// 2-layer ReLU RNN, B=256, T=1000 (input 800 + zero pad), H=128, F=5.
// R3: MFMA rewrite. One block per batch element, 12 waves = 3 engines x 4
// waves (w_hh0+w_ih0 / w_ih1 / w_hh1), same 2-step-skew schedule as R2.
// Each wave owns 32 output rows (2 row-tiles of 16): GEMV via
// mfma_f32_16x16x32_bf16 with weight fragments resident in regs and the
// h-vector broadcast across the 16 B-columns. Verified layouts (learn_hip
// m89/m91/m120): A[m=lane&15][k=(lane>>4)*8+j]; C/D col=lane&15,
// row=(lane>>4)*4+reg. Layer-0 x-term folded in as a 5th k-tile.
// fp32 kept for: A_lds (layer-1 pre-activation), final h-states, biases.

#define TT    1000
#define TIN   800
#define HD    128
#define NF    5
#define BATCH 256

typedef float f32x4 __attribute__((ext_vector_type(4)));
typedef short s16x8 __attribute__((ext_vector_type(8)));

__device__ __forceinline__ unsigned short f2bf(float f) {
    union { float f; unsigned int u; } c; c.f = f;
    unsigned int r = (c.u + 0x7FFFu + ((c.u >> 16) & 1u)) >> 16;  // RNE
    return (unsigned short)r;
}
__device__ __forceinline__ float bf2f(unsigned short h) {
    union { unsigned int u; float f; } c; c.u = ((unsigned int)h) << 16;
    return c.f;
}

__global__ __launch_bounds__(768, 3) void rnn_mfma(
    const float* __restrict__ x,        // [256,800,5]
    const float* __restrict__ h_state,  // [2,256,128]
    const float* __restrict__ w_ih0,    // [128,5]
    const float* __restrict__ w_hh0,    // [128,128]
    const float* __restrict__ b_ih0,    // [128]
    const float* __restrict__ b_hh0,    // [128]
    const float* __restrict__ w_ih1,    // [128,128]
    const float* __restrict__ w_hh1,    // [128,128]
    const float* __restrict__ b_ih1,    // [128]
    const float* __restrict__ b_hh1,    // [128]
    const float* __restrict__ w_out,    // [1,128]
    const float* __restrict__ b_out,    // [1]
    float* __restrict__ out)            // [204800 y] ++ [65536 final states]
{
    __shared__ __align__(16) unsigned short x_bf[TIN * 8];  // stride 8, 12.8KB
    __shared__ __align__(16) unsigned short h0b[2][HD];
    __shared__ __align__(16) unsigned short h1b[2][HD];
    __shared__ __align__(16) float A_f[2][HD];              // fp32 pre-act
    __shared__ __align__(16) unsigned short ring[16][HD];   // h1 history (bf16)
    __shared__ float wout_lds[HD];
    __shared__ __align__(16) float h0f[HD], h1f[HD];        // fp32 final states

    const int tid = threadIdx.x;
    const int bb  = blockIdx.x;
    const int wv  = tid >> 6;       // 0..11
    const int e   = wv >> 2;        // engine 0..2
    const int ww  = wv & 3;         // wave within engine -> rows 32*ww..+31
    const int l   = tid & 63;
    const int m   = l & 15;         // A row within tile / C col
    const int q4  = l >> 4;         // k sub-chunk / C row group
    const bool wr = (m == 0);       // C col 0 -> writer lane
    const int lt  = tid & 255;      // index within engine (y-dots)

    // ---- stage x as bf16, stride 8 (zeros in pad lanes) ----
    for (int i = tid; i < TIN * 8; i += 768) x_bf[i] = 0;
    __syncthreads();
    for (int i = tid; i < TIN * NF; i += 768) {
        int t = i / 5, f = i - 5 * t;
        x_bf[t * 8 + f] = f2bf(x[bb * (TIN * NF) + i]);
    }
    if (tid < HD) {
        float v0 = h_state[bb * HD + tid];
        float v1 = h_state[BATCH * HD + bb * HD + tid];
        h0b[0][tid] = f2bf(v0);
        h1b[0][tid] = f2bf(v1);
        h0f[tid] = v0; h1f[tid] = v1;
    } else if (tid < 2 * HD) {
        wout_lds[tid - HD] = w_out[tid - HD];
    }

    // ---- resident A fragments (bf16): A[rt][kt], k = kt*32 + q4*8 + j ----
    const float* Wsrc = (e == 0) ? w_hh0 : ((e == 1) ? w_ih1 : w_hh1);
    s16x8 A[2][5];
    #pragma unroll
    for (int rt = 0; rt < 2; ++rt) {
        const int row = 32 * ww + 16 * rt + m;
        #pragma unroll
        for (int kt = 0; kt < 4; ++kt) {
            const float* rp = Wsrc + row * HD + kt * 32 + q4 * 8;
            s16x8 a;
            #pragma unroll
            for (int j = 0; j < 8; ++j) a[j] = (short)f2bf(rp[j]);
            A[rt][kt] = a;
        }
        s16x8 a4 = {0, 0, 0, 0, 0, 0, 0, 0};   // layer-0 x columns (k-tile 4)
        if (e == 0 && q4 == 0) {
            #pragma unroll
            for (int j = 0; j < NF; ++j) a4[j] = (short)f2bf(w_ih0[row * NF + j]);
        }
        A[rt][4] = a4;
    }

    // ---- biases for my writer rows: r0 = 32*ww + 16*rt + q4*4 ----
    f32x4 bias[2] = {{0,0,0,0},{0,0,0,0}};
    if (e == 0) {
        #pragma unroll
        for (int rt = 0; rt < 2; ++rt) {
            const int r0 = 32 * ww + 16 * rt + q4 * 4;
            #pragma unroll
            for (int j = 0; j < 4; ++j) bias[rt][j] = b_ih0[r0 + j] + b_hh0[r0 + j];
        }
    } else if (e == 2) {
        #pragma unroll
        for (int rt = 0; rt < 2; ++rt) {
            const int r0 = 32 * ww + 16 * rt + q4 * 4;
            #pragma unroll
            for (int j = 0; j < 4; ++j) bias[rt][j] = b_ih1[r0 + j] + b_hh1[r0 + j];
        }
    }
    const float bout = b_out[0];
    const int r0 = 32 * ww + q4 * 4;   // rt=0 writer row base (rt=1: +16)

    __syncthreads();

    #pragma unroll 2
    for (int s = 0; s < TT + 2; ++s) {
        const int p = s & 1;
        const int q = p ^ 1;

        if (e == 0) {
            // h0[s] = relu(Whh0.h0[s-1] + Wih0.x[s] + b)
            if (s < TT) {
                const unsigned short* hb = h0b[p];
                f32x4 D0 = {0,0,0,0}, D1 = {0,0,0,0};
                #pragma unroll
                for (int kt = 0; kt < 4; ++kt) {
                    s16x8 B = *(const s16x8*)(hb + kt * 32 + q4 * 8);
                    D0 = __builtin_amdgcn_mfma_f32_16x16x32_bf16(A[0][kt], B, D0, 0, 0, 0);
                    D1 = __builtin_amdgcn_mfma_f32_16x16x32_bf16(A[1][kt], B, D1, 0, 0, 0);
                }
                if (s < TIN) {
                    s16x8 xb = *(const s16x8*)(x_bf + s * 8);
                    s16x8 z  = {0,0,0,0,0,0,0,0};
                    s16x8 Bx = (q4 == 0) ? xb : z;
                    D0 = __builtin_amdgcn_mfma_f32_16x16x32_bf16(A[0][4], Bx, D0, 0, 0, 0);
                    D1 = __builtin_amdgcn_mfma_f32_16x16x32_bf16(A[1][4], Bx, D1, 0, 0, 0);
                }
                f32x4 v0, v1;
                #pragma unroll
                for (int j = 0; j < 4; ++j) {
                    v0[j] = fmaxf(D0[j] + bias[0][j], 0.f);
                    v1[j] = fmaxf(D1[j] + bias[1][j], 0.f);
                }
                if (wr) {
                    uint2 p0 = { (unsigned)f2bf(v0[0]) | ((unsigned)f2bf(v0[1]) << 16),
                                 (unsigned)f2bf(v0[2]) | ((unsigned)f2bf(v0[3]) << 16) };
                    uint2 p1 = { (unsigned)f2bf(v1[0]) | ((unsigned)f2bf(v1[1]) << 16),
                                 (unsigned)f2bf(v1[2]) | ((unsigned)f2bf(v1[3]) << 16) };
                    *(uint2*)(h0b[q] + r0)      = p0;
                    *(uint2*)(h0b[q] + r0 + 16) = p1;
                    *(f32x4*)(h0f + r0)      = v0;
                    *(f32x4*)(h0f + r0 + 16) = v1;
                }
            }
        } else if (e == 1) {
            // A[s-1] = Wih1 . h0[s-1]   (fp32 pre-activation)
            if (s <= TT) {
                const unsigned short* hb = h0b[p];
                f32x4 D0 = {0,0,0,0}, D1 = {0,0,0,0};
                #pragma unroll
                for (int kt = 0; kt < 4; ++kt) {
                    s16x8 B = *(const s16x8*)(hb + kt * 32 + q4 * 8);
                    D0 = __builtin_amdgcn_mfma_f32_16x16x32_bf16(A[0][kt], B, D0, 0, 0, 0);
                    D1 = __builtin_amdgcn_mfma_f32_16x16x32_bf16(A[1][kt], B, D1, 0, 0, 0);
                }
                if (wr) {
                    *(f32x4*)(&A_f[q][r0])      = D0;
                    *(f32x4*)(&A_f[q][r0 + 16]) = D1;
                }
            }
            // batched y-dots: 8 sigmoids per visit, every 8th step
            if (s >= 10 && s <= 802 && ((s - 2) & 7) == 0) {
                const int u  = (s - 10) + (lt >> 5);
                const int l5 = lt & 31;
                const unsigned short* hr = ring[u & 15];
                float v = bf2f(hr[l5      ]) * wout_lds[l5      ]
                        + bf2f(hr[l5 + 32]) * wout_lds[l5 + 32]
                        + bf2f(hr[l5 + 64]) * wout_lds[l5 + 64]
                        + bf2f(hr[l5 + 96]) * wout_lds[l5 + 96];
                v += __shfl_xor(v, 16, 64);
                v += __shfl_xor(v,  8, 64);
                v += __shfl_xor(v,  4, 64);
                v += __shfl_xor(v,  2, 64);
                v += __shfl_xor(v,  1, 64);
                if (l5 == 0) {
                    float zz = v + bout;
                    out[bb * TIN + u] = 1.f / (1.f + expf(-zz));
                }
            }
        } else {
            // h1[s-2] = relu(A[s-2] + Whh1.h1[s-3] + b)
            if (s >= 2) {
                const int u = s - 2;
                const unsigned short* hb = h1b[p];
                f32x4 D0 = {0,0,0,0}, D1 = {0,0,0,0};
                #pragma unroll
                for (int kt = 0; kt < 4; ++kt) {
                    s16x8 B = *(const s16x8*)(hb + kt * 32 + q4 * 8);
                    D0 = __builtin_amdgcn_mfma_f32_16x16x32_bf16(A[0][kt], B, D0, 0, 0, 0);
                    D1 = __builtin_amdgcn_mfma_f32_16x16x32_bf16(A[1][kt], B, D1, 0, 0, 0);
                }
                f32x4 a40 = *(const f32x4*)(&A_f[p][r0]);
                f32x4 a41 = *(const f32x4*)(&A_f[p][r0 + 16]);
                f32x4 v0, v1;
                #pragma unroll
                for (int j = 0; j < 4; ++j) {
                    v0[j] = fmaxf(D0[j] + bias[0][j] + a40[j], 0.f);
                    v1[j] = fmaxf(D1[j] + bias[1][j] + a41[j], 0.f);
                }
                if (wr) {
                    uint2 p0 = { (unsigned)f2bf(v0[0]) | ((unsigned)f2bf(v0[1]) << 16),
                                 (unsigned)f2bf(v0[2]) | ((unsigned)f2bf(v0[3]) << 16) };
                    uint2 p1 = { (unsigned)f2bf(v1[0]) | ((unsigned)f2bf(v1[1]) << 16),
                                 (unsigned)f2bf(v1[2]) | ((unsigned)f2bf(v1[3]) << 16) };
                    *(uint2*)(h1b[q] + r0)      = p0;
                    *(uint2*)(h1b[q] + r0 + 16) = p1;
                    *(f32x4*)(h1f + r0)      = v0;
                    *(f32x4*)(h1f + r0 + 16) = v1;
                    if (u < TIN) {
                        *(uint2*)(ring[u & 15] + r0)      = p0;
                        *(uint2*)(ring[u & 15] + r0 + 16) = p1;
                    }
                }
            }
        }
        __syncthreads();
    }

    // h0f = h0[999] (s=999), h1f = h1[999] (s=1001)
    if (tid < HD) {
        out[TIN * BATCH + bb * HD + tid] = h0f[tid];
    } else if (tid < 2 * HD) {
        out[TIN * BATCH + BATCH * HD + bb * HD + (tid - HD)] = h1f[tid - HD];
    }
}

extern "C" void kernel_launch(void* const* d_in, const int* in_sizes, int n_in,
                              void* d_out, int out_size, void* d_ws, size_t ws_size,
                              hipStream_t stream) {
    (void)in_sizes; (void)n_in; (void)d_ws; (void)ws_size; (void)out_size;
    rnn_mfma<<<dim3(BATCH), dim3(768), 0, stream>>>(
        (const float*)d_in[0],  (const float*)d_in[1],
        (const float*)d_in[2],  (const float*)d_in[3],
        (const float*)d_in[4],  (const float*)d_in[5],
        (const float*)d_in[6],  (const float*)d_in[7],
        (const float*)d_in[8],  (const float*)d_in[9],
        (const float*)d_in[10], (const float*)d_in[11],
        (float*)d_out);
}

// Round 4
// 603.008 us; speedup vs baseline: 1.1602x; 1.1602x over previous
//
#include <hip/hip_runtime.h>
#include <hip/hip_bf16.h>
#include <math.h>

// 2-layer ReLU RNN, B=256, T=1000 (input 800 + zero pad), H=128, F=5.
// R4: MFMA 3-engine skew (verified R3) + stall/VALU cleanup:
//  - 16 waves: e0 = 8 waves x 1 rowtile (5 MFMA), e1/e2 = 4 waves x 2 rowtiles
//    (8 MFMA). Per SIMD {e0,e0,e1,e2} = 26 MFMA = 504 cyc pipe floor.
//  - No global memory ops inside the step loop (y -> y_lds, finals -> regs):
//    the loop barrier never waits vmcnt(0).
//  - v_cvt_pk_bf16_f32 via __float22bfloat162_rn for h repack.
//  - x-tile: A kt4 fragment is zero for q4!=0 lanes, so B needs no masking.
// Layouts (learn_hip m89/m91): A[m=lane&15][k=(lane>>4)*8+j];
// C/D col=lane&15, row=(lane>>4)*4+reg. B reads are 16B broadcasts (0 conflicts).

#define TT    1000
#define TIN   800
#define HD    128
#define NF    5
#define BATCH 256

typedef float f32x4 __attribute__((ext_vector_type(4)));
typedef short s16x8 __attribute__((ext_vector_type(8)));

__device__ __forceinline__ unsigned short f2bf(float f) {
    union { float f; unsigned int u; } c; c.f = f;
    unsigned int r = (c.u + 0x7FFFu + ((c.u >> 16) & 1u)) >> 16;  // RNE
    return (unsigned short)r;
}
__device__ __forceinline__ float bf2f(unsigned short h) {
    union { unsigned int u; float f; } c; c.u = ((unsigned int)h) << 16;
    return c.f;
}
__device__ __forceinline__ unsigned pk2bf(float a, float b) {
    union { __hip_bfloat162 h; unsigned u; } c;
    c.h = __float22bfloat162_rn(make_float2(a, b));   // v_cvt_pk_bf16_f32
    return c.u;
}

__global__ __launch_bounds__(1024, 4) void rnn_mfma(
    const float* __restrict__ x,        // [256,800,5]
    const float* __restrict__ h_state,  // [2,256,128]
    const float* __restrict__ w_ih0,    // [128,5]
    const float* __restrict__ w_hh0,    // [128,128]
    const float* __restrict__ b_ih0,    // [128]
    const float* __restrict__ b_hh0,    // [128]
    const float* __restrict__ w_ih1,    // [128,128]
    const float* __restrict__ w_hh1,    // [128,128]
    const float* __restrict__ b_ih1,    // [128]
    const float* __restrict__ b_hh1,    // [128]
    const float* __restrict__ w_out,    // [1,128]
    const float* __restrict__ b_out,    // [1]
    float* __restrict__ out)            // [204800 y] ++ [65536 final states]
{
    __shared__ __align__(16) unsigned short x_bf[TIN * 8];  // 12.8 KB
    __shared__ __align__(16) unsigned short h0b[2][HD];
    __shared__ __align__(16) unsigned short h1b[2][HD];
    __shared__ __align__(16) float A_f[2][HD];              // fp32 pre-act
    __shared__ __align__(16) unsigned short ring[16][HD];   // h1 history bf16
    __shared__ float wout_lds[HD];
    __shared__ float y_lds[TIN];                            // 3.2 KB

    const int tid = threadIdx.x;
    const int bb  = blockIdx.x;
    const int wv  = tid >> 6;       // 0..15
    const int l   = tid & 63;
    const int m   = l & 15;         // A row within tile / C col
    const int q4  = l >> 4;
    const bool wr = (m == 0);       // C col 0 -> writer lane
    const int lt  = tid - 512;      // e1 intra-engine index (0..255 valid)

    // ---- stage x as bf16, stride 8 ----
    for (int i = tid; i < TIN * 8; i += 1024) x_bf[i] = 0;
    __syncthreads();
    for (int i = tid; i < TIN * NF; i += 1024) {
        int t = i / 5, f = i - 5 * t;
        x_bf[t * 8 + f] = f2bf(x[bb * (TIN * NF) + i]);
    }
    if (tid < HD) {
        h0b[0][tid] = f2bf(h_state[bb * HD + tid]);
        h1b[0][tid] = f2bf(h_state[BATCH * HD + bb * HD + tid]);
    } else if (tid < 2 * HD) {
        wout_lds[tid - HD] = w_out[tid - HD];
    }

    // ---- resident A fragments (bf16) + biases ----
    s16x8 A0[5];          // e0: 1 rowtile, 4 k-tiles + x-tile
    s16x8 A1[2][4];       // e1/e2: 2 rowtiles x 4 k-tiles
    f32x4 bias0 = {0,0,0,0}, bias1 = {0,0,0,0};
    int r0;

    if (wv < 8) {
        const int row = 16 * wv + m;
        r0 = 16 * wv + 4 * q4;
        #pragma unroll
        for (int kt = 0; kt < 4; ++kt) {
            const float* rp = w_hh0 + row * HD + kt * 32 + q4 * 8;
            s16x8 a;
            #pragma unroll
            for (int j = 0; j < 8; ++j) a[j] = (short)f2bf(rp[j]);
            A0[kt] = a;
        }
        s16x8 a4 = {0,0,0,0,0,0,0,0};
        if (q4 == 0) {
            #pragma unroll
            for (int j = 0; j < NF; ++j) a4[j] = (short)f2bf(w_ih0[row * NF + j]);
        }
        A0[4] = a4;
        #pragma unroll
        for (int j = 0; j < 4; ++j) bias0[j] = b_ih0[r0 + j] + b_hh0[r0 + j];
    } else {
        const bool ee = (wv >= 12);          // e2?
        const int ww = wv - (ee ? 12 : 8);
        r0 = 32 * ww + 4 * q4;
        const float* W = ee ? w_hh1 : w_ih1;
        #pragma unroll
        for (int rt = 0; rt < 2; ++rt) {
            const int row = 32 * ww + 16 * rt + m;
            #pragma unroll
            for (int kt = 0; kt < 4; ++kt) {
                const float* rp = W + row * HD + kt * 32 + q4 * 8;
                s16x8 a;
                #pragma unroll
                for (int j = 0; j < 8; ++j) a[j] = (short)f2bf(rp[j]);
                A1[rt][kt] = a;
            }
        }
        if (ee) {
            #pragma unroll
            for (int j = 0; j < 4; ++j) {
                bias0[j] = b_ih1[r0 + j] + b_hh1[r0 + j];
                bias1[j] = b_ih1[r0 + 16 + j] + b_hh1[r0 + 16 + j];
            }
        }
    }
    const float bout = b_out[0];

    f32x4 hfin0  = {0,0,0,0};            // e0 writer: h0[999]
    f32x4 hfin1a = {0,0,0,0};            // e2 writer: h1[999] rows r0..r0+3
    f32x4 hfin1b = {0,0,0,0};            //            rows r0+16..r0+19

    __syncthreads();

    #pragma unroll 2
    for (int s = 0; s < TT + 2; ++s) {
        const int p = s & 1;
        const int q = p ^ 1;

        if (wv < 8) {
            // e0: h0[s] = relu(Whh0.h0[s-1] + Wih0.x[s] + b)
            if (s < TT) {
                const unsigned short* hb = h0b[p];
                s16x8 B0 = *(const s16x8*)(hb +      q4 * 8);
                s16x8 B1 = *(const s16x8*)(hb + 32 + q4 * 8);
                s16x8 B2 = *(const s16x8*)(hb + 64 + q4 * 8);
                s16x8 B3 = *(const s16x8*)(hb + 96 + q4 * 8);
                f32x4 Da = {0,0,0,0}, Db = {0,0,0,0};
                Da = __builtin_amdgcn_mfma_f32_16x16x32_bf16(A0[0], B0, Da, 0, 0, 0);
                Db = __builtin_amdgcn_mfma_f32_16x16x32_bf16(A0[1], B1, Db, 0, 0, 0);
                Da = __builtin_amdgcn_mfma_f32_16x16x32_bf16(A0[2], B2, Da, 0, 0, 0);
                Db = __builtin_amdgcn_mfma_f32_16x16x32_bf16(A0[3], B3, Db, 0, 0, 0);
                if (s < TIN) {
                    s16x8 Bx = *(const s16x8*)(x_bf + s * 8);   // A0[4]=0 off q4==0
                    Da = __builtin_amdgcn_mfma_f32_16x16x32_bf16(A0[4], Bx, Da, 0, 0, 0);
                }
                f32x4 v;
                #pragma unroll
                for (int j = 0; j < 4; ++j)
                    v[j] = fmaxf(Da[j] + Db[j] + bias0[j], 0.f);
                if (wr) {
                    hfin0 = v;
                    *(uint2*)(h0b[q] + r0) =
                        make_uint2(pk2bf(v[0], v[1]), pk2bf(v[2], v[3]));
                }
            }
        } else if (wv < 12) {
            // e1: A[s-1] = Wih1 . h0[s-1]  (fp32 pre-activation)
            if (s <= TT) {
                const unsigned short* hb = h0b[p];
                f32x4 D0 = {0,0,0,0}, D1 = {0,0,0,0};
                #pragma unroll
                for (int kt = 0; kt < 4; ++kt) {
                    s16x8 B = *(const s16x8*)(hb + kt * 32 + q4 * 8);
                    D0 = __builtin_amdgcn_mfma_f32_16x16x32_bf16(A1[0][kt], B, D0, 0, 0, 0);
                    D1 = __builtin_amdgcn_mfma_f32_16x16x32_bf16(A1[1][kt], B, D1, 0, 0, 0);
                }
                if (wr) {
                    *(f32x4*)(&A_f[q][r0])      = D0;
                    *(f32x4*)(&A_f[q][r0 + 16]) = D1;
                }
            }
            // batched y-dots from ring, 8 steps per visit -> y_lds
            if (s >= 10 && s <= 802 && ((s - 2) & 7) == 0) {
                const int u  = (s - 10) + (lt >> 5);
                const int l5 = lt & 31;
                const unsigned short* hr = ring[u & 15];
                float v = bf2f(hr[l5      ]) * wout_lds[l5      ]
                        + bf2f(hr[l5 + 32]) * wout_lds[l5 + 32]
                        + bf2f(hr[l5 + 64]) * wout_lds[l5 + 64]
                        + bf2f(hr[l5 + 96]) * wout_lds[l5 + 96];
                v += __shfl_xor(v, 16, 64);
                v += __shfl_xor(v,  8, 64);
                v += __shfl_xor(v,  4, 64);
                v += __shfl_xor(v,  2, 64);
                v += __shfl_xor(v,  1, 64);
                if (l5 == 0) y_lds[u] = 1.f / (1.f + expf(-(v + bout)));
            }
        } else {
            // e2: h1[s-2] = relu(A[s-2] + Whh1.h1[s-3] + b)
            if (s >= 2) {
                const int u = s - 2;
                const unsigned short* hb = h1b[p];
                f32x4 D0 = {0,0,0,0}, D1 = {0,0,0,0};
                #pragma unroll
                for (int kt = 0; kt < 4; ++kt) {
                    s16x8 B = *(const s16x8*)(hb + kt * 32 + q4 * 8);
                    D0 = __builtin_amdgcn_mfma_f32_16x16x32_bf16(A1[0][kt], B, D0, 0, 0, 0);
                    D1 = __builtin_amdgcn_mfma_f32_16x16x32_bf16(A1[1][kt], B, D1, 0, 0, 0);
                }
                f32x4 a0 = *(const f32x4*)(&A_f[p][r0]);
                f32x4 a1 = *(const f32x4*)(&A_f[p][r0 + 16]);
                f32x4 v0, v1;
                #pragma unroll
                for (int j = 0; j < 4; ++j) {
                    v0[j] = fmaxf(D0[j] + bias0[j] + a0[j], 0.f);
                    v1[j] = fmaxf(D1[j] + bias1[j] + a1[j], 0.f);
                }
                if (wr) {
                    hfin1a = v0; hfin1b = v1;
                    uint2 p0 = make_uint2(pk2bf(v0[0], v0[1]), pk2bf(v0[2], v0[3]));
                    uint2 p1 = make_uint2(pk2bf(v1[0], v1[1]), pk2bf(v1[2], v1[3]));
                    *(uint2*)(h1b[q] + r0)      = p0;
                    *(uint2*)(h1b[q] + r0 + 16) = p1;
                    if (u < TIN) {
                        *(uint2*)(ring[u & 15] + r0)      = p0;
                        *(uint2*)(ring[u & 15] + r0 + 16) = p1;
                    }
                }
            }
        }
        __syncthreads();
    }

    // ---- epilogue: single global dump ----
    for (int i = tid; i < TIN; i += 1024)
        out[bb * TIN + i] = y_lds[i];
    if (wv < 8 && wr)
        *(f32x4*)(out + TIN * BATCH + bb * HD + r0) = hfin0;
    if (wv >= 12 && wr) {
        *(f32x4*)(out + TIN * BATCH + BATCH * HD + bb * HD + r0)      = hfin1a;
        *(f32x4*)(out + TIN * BATCH + BATCH * HD + bb * HD + r0 + 16) = hfin1b;
    }
}

extern "C" void kernel_launch(void* const* d_in, const int* in_sizes, int n_in,
                              void* d_out, int out_size, void* d_ws, size_t ws_size,
                              hipStream_t stream) {
    (void)in_sizes; (void)n_in; (void)d_ws; (void)ws_size; (void)out_size;
    rnn_mfma<<<dim3(BATCH), dim3(1024), 0, stream>>>(
        (const float*)d_in[0],  (const float*)d_in[1],
        (const float*)d_in[2],  (const float*)d_in[3],
        (const float*)d_in[4],  (const float*)d_in[5],
        (const float*)d_in[6],  (const float*)d_in[7],
        (const float*)d_in[8],  (const float*)d_in[9],
        (const float*)d_in[10], (const float*)d_in[11],
        (float*)d_out);
}